// Round 3
// baseline (32.503 us; speedup 1.0000x reference)
//
#include <hip/hip_runtime.h>
#include <hip/hip_bf16.h>

// out[a,b] = sum_i max_j <pano_n[a,i,:], sat_n[b,j,:]>
// d_in[0] sat  [256,64,128] fp32 -> 16384 rows (j, GEMM M / C-rows, streamed via LDS)
// d_in[1] pano [ 64,64,128] fp32 ->  4096 rows (i, GEMM N / C-cols, held in VGPRs)
// out [64,256] fp32

typedef __bf16 bf16x8 __attribute__((ext_vector_type(8)));
typedef float  f32x16 __attribute__((ext_vector_type(16)));
typedef unsigned int u32;

__device__ __forceinline__ void gload16(const void* g, void* l) {
    __builtin_amdgcn_global_load_lds((const __attribute__((address_space(1))) u32*)g,
                                     (__attribute__((address_space(3))) u32*)l, 16, 0, 0);
}

__device__ __forceinline__ unsigned short f2bf_rne(float x) {
    u32 u = __builtin_bit_cast(u32, x);
    return (unsigned short)((u + 0x7FFFu + ((u >> 16) & 1u)) >> 16);
}

// 32 lanes per row of 128 floats: L2-normalize, emit bf16. Handles both tensors.
__global__ __launch_bounds__(256) void normalize_all(
        const float* __restrict__ sat, const float* __restrict__ pano,
        unsigned short* __restrict__ satN, unsigned short* __restrict__ panoN) {
    int row  = blockIdx.x * 8 + (threadIdx.x >> 5);
    int lane = threadIdx.x & 31;
    const float* src;
    unsigned short* dst;
    if (row < 16384) { src = sat  + (size_t)row * 128;           dst = satN  + (size_t)row * 128; }
    else             { src = pano + (size_t)(row - 16384) * 128; dst = panoN + (size_t)(row - 16384) * 128; }
    const float4 v = *reinterpret_cast<const float4*>(src + lane * 4);
    float ss = v.x * v.x + v.y * v.y + v.z * v.z + v.w * v.w;
    #pragma unroll
    for (int m = 16; m >= 1; m >>= 1) ss += __shfl_xor(ss, m);
    float sc = 1.0f / fmaxf(sqrtf(ss), 1e-12f);
    ushort4 o;
    o.x = f2bf_rne(v.x * sc); o.y = f2bf_rne(v.y * sc);
    o.z = f2bf_rne(v.z * sc); o.w = f2bf_rne(v.w * sc);
    *reinterpret_cast<ushort4*>(dst + lane * 4) = o;
}

// 512 blocks x 256 threads (4 waves), 2 blocks/CU resident (64 KB LDS each).
// Block = (sat group jg: 4 tiles of 256 j-rows) x (pano panel it: 128 i-cols).
// Pano B-fragments in VGPRs (loaded once); sat streamed through 2x32KB K-half LDS buffers
// via global_load_lds (linear dest + inverse-XOR-swizzled source, XOR-swizzled reads).
// A=sat (C rows=j): max_j is within-lane over acc regs; sum_i is one butterfly.
__global__ __launch_bounds__(256, 2) void maxsim_kernel(
        const unsigned short* __restrict__ satN,
        const unsigned short* __restrict__ panoN,
        float* __restrict__ out) {
    __shared__ unsigned short Slds[2][256 * 64];   // 2 x 32 KB sat K-halves, 8-slot swizzle

    const int tid  = threadIdx.x;
    const int wid  = tid >> 6;
    const int lane = tid & 63;
    const int rl   = lane & 31;
    const int hi   = lane >> 5;

    const int bid = blockIdx.x;
    const int swz = (bid & 7) * 64 + (bid >> 3);   // XCD-contiguous logical id (512%8==0)
    const int jg  = swz >> 5;                      // 0..15 sat group (tiles jg*4..jg*4+3)
    const int it  = swz & 31;                      // 0..31 pano panel (128 i-cols)

    const int wm = wid >> 1;                       // 0..1 j-half (128 rows)
    const int wn = wid & 1;                        // 0..1 i-half (64 cols = one a)

    // ---- B (pano) fragments: 64 i-cols x K=128 per wave, 64 VGPR, loaded once ----
    bf16x8 bfr[2][8];
    {
        const unsigned short* pb =
            panoN + ((size_t)(it * 128 + wn * 64 + rl)) * 128 + hi * 8;
        #pragma unroll
        for (int n = 0; n < 2; ++n)
            #pragma unroll
            for (int kf = 0; kf < 8; ++kf)
                bfr[n][kf] = *reinterpret_cast<const bf16x8*>(pb + n * 32 * 128 + kf * 16);
    }

#define STAGE(st, kh) do {                                                     \
    const char* gb_ = (const char*)satN + (size_t)(st) * 65536 + (kh) * 128;   \
    char* lb_ = (char*)&Slds[kh][0];                                           \
    _Pragma("unroll")                                                          \
    for (int i_ = 0; i_ < 8; ++i_) {                                           \
        int P_ = (wid * 8 + i_) * 1024 + lane * 16;                            \
        int r_ = P_ >> 7;                                                      \
        int g_ = ((P_ >> 4) & 7) ^ (r_ & 7);                                   \
        gload16(gb_ + (size_t)r_ * 256 + g_ * 16, lb_ + P_);                   \
    } } while (0)

#define COMPUTE(kh) do {                                                       \
    const char* sb_ = (const char*)&Slds[kh][0];                               \
    _Pragma("unroll")                                                          \
    for (int ks = 0; ks < 4; ++ks) {                                           \
        bf16x8 a_[4];                                                          \
        _Pragma("unroll")                                                      \
        for (int m = 0; m < 4; ++m) {                                          \
            int row = wm * 128 + m * 32 + rl;                                  \
            a_[m] = *(const bf16x8*)(sb_ + row * 128 + ((((ks << 1) | hi) ^ (row & 7)) << 4)); \
        }                                                                      \
        _Pragma("unroll")                                                      \
        for (int m = 0; m < 4; ++m)                                            \
            _Pragma("unroll")                                                  \
            for (int n = 0; n < 2; ++n)                                        \
                acc[m][n] = __builtin_amdgcn_mfma_f32_32x32x16_bf16(           \
                    a_[m], bfr[n][(kh) * 4 + ks], acc[m][n], 0, 0, 0);         \
    } } while (0)

    STAGE(jg * 4, 0);
    __syncthreads();

    for (int t = 0; t < 4; ++t) {
        const int st = jg * 4 + t;
        f32x16 acc[4][2] = {};

        STAGE(st, 1);                       // lands during COMPUTE(0)
        __builtin_amdgcn_sched_barrier(0);
        COMPUTE(0);
        __syncthreads();

        if (t < 3) {
            STAGE(st + 1, 0);               // lands during COMPUTE(1)
            __builtin_amdgcn_sched_barrier(0);
        }
        COMPUTE(1);
        __syncthreads();

        // epilogue: max_j within-lane (+hi-swap), sum_i butterfly over 32 col-lanes
        // C layout 32x32: row=(q&3)+8*(q>>2)+4*hi, col=lane&31
        #pragma unroll
        for (int jb = 0; jb < 2; ++jb) {
            float v0 = acc[2 * jb][0][0];
            float v1 = acc[2 * jb][1][0];
            #pragma unroll
            for (int m = 2 * jb; m <= 2 * jb + 1; ++m)
                #pragma unroll
                for (int q = 0; q < 16; ++q) {
                    if (m == 2 * jb && q == 0) continue;
                    v0 = fmaxf(v0, acc[m][0][q]);
                    v1 = fmaxf(v1, acc[m][1][q]);
                }
            v0 = fmaxf(v0, __shfl_xor(v0, 32));
            v1 = fmaxf(v1, __shfl_xor(v1, 32));
            float s = v0 + v1;
            #pragma unroll
            for (int d = 1; d <= 16; d <<= 1) s += __shfl_xor(s, d);
            if (lane == 0) {
                int a = it * 2 + wn;
                int b = st * 4 + wm * 2 + jb;
                out[a * 256 + b] = s;
            }
        }
    }
#undef STAGE
#undef COMPUTE
}

extern "C" void kernel_launch(void* const* d_in, const int* in_sizes, int n_in,
                              void* d_out, int out_size, void* d_ws, size_t ws_size,
                              hipStream_t stream) {
    const float* sat  = (const float*)d_in[0];   // [16384,128]
    const float* pano = (const float*)d_in[1];   // [ 4096,128]
    float* out = (float*)d_out;                  // [64,256]

    unsigned short* panoN = (unsigned short*)d_ws;        // 4096*128 bf16
    unsigned short* satN  = panoN + (size_t)4096 * 128;   // 16384*128 bf16

    normalize_all<<<2560, 256, 0, stream>>>(sat, pano, satN, panoN);
    maxsim_kernel<<<512, 256, 0, stream>>>(satN, panoN, out);
}

// Round 4
// 29.804 us; speedup vs baseline: 1.0906x; 1.0906x over previous
//
#include <hip/hip_runtime.h>
#include <hip/hip_bf16.h>

// out[a,b] = sum_i max_j_in_image_b <pano_n[a,i,:], sat_n[b,j,:]>
// d_in[0] sat  [256,64,128] fp32 -> 16384 rows (j, GEMM M / C-rows, streamed via LDS)
// d_in[1] pano [ 64,64,128] fp32 ->  4096 rows (i, GEMM N / C-cols, held in VGPRs)
// out [64,256] fp32

typedef __bf16 bf16x8 __attribute__((ext_vector_type(8)));
typedef float  f32x16 __attribute__((ext_vector_type(16)));
typedef unsigned int u32;

__device__ __forceinline__ void gload16(const void* g, void* l) {
    __builtin_amdgcn_global_load_lds((const __attribute__((address_space(1))) u32*)g,
                                     (__attribute__((address_space(3))) u32*)l, 16, 0, 0);
}

__device__ __forceinline__ unsigned short f2bf_rne(float x) {
    u32 u = __builtin_bit_cast(u32, x);
    return (unsigned short)((u + 0x7FFFu + ((u >> 16) & 1u)) >> 16);
}

// 32 lanes per row of 128 floats: L2-normalize, emit bf16. Handles both tensors.
__global__ __launch_bounds__(256) void normalize_all(
        const float* __restrict__ sat, const float* __restrict__ pano,
        unsigned short* __restrict__ satN, unsigned short* __restrict__ panoN) {
    int row  = blockIdx.x * 8 + (threadIdx.x >> 5);
    int lane = threadIdx.x & 31;
    const float* src;
    unsigned short* dst;
    if (row < 16384) { src = sat  + (size_t)row * 128;           dst = satN  + (size_t)row * 128; }
    else             { src = pano + (size_t)(row - 16384) * 128; dst = panoN + (size_t)(row - 16384) * 128; }
    const float4 v = *reinterpret_cast<const float4*>(src + lane * 4);
    float ss = v.x * v.x + v.y * v.y + v.z * v.z + v.w * v.w;
    #pragma unroll
    for (int m = 16; m >= 1; m >>= 1) ss += __shfl_xor(ss, m);
    float sc = 1.0f / fmaxf(sqrtf(ss), 1e-12f);
    ushort4 o;
    o.x = f2bf_rne(v.x * sc); o.y = f2bf_rne(v.y * sc);
    o.z = f2bf_rne(v.z * sc); o.w = f2bf_rne(v.w * sc);
    *reinterpret_cast<ushort4*>(dst + lane * 4) = o;
}

// 512 blocks x 256 threads (4 waves = 2wm x 2wn), 2 blocks/CU (32 KB LDS each).
// Block = (jg: 8 streamed sat tiles of 128 j-rows) x (it: 128 pano i-cols).
// Wave tile 64j x 64i: acc 64 VGPR + pano B-frags 64 VGPR (loaded once) -> ~165 live, no spill.
// Sat streamed via 2 x 16 KB K-half LDS buffers, global_load_lds linear dest +
// inverse-XOR-swizzled source, XOR-swizzled reads (bank-balanced).
// A=sat (C rows=j): max_j within-lane over acc regs; sum_i one butterfly.
__global__ __launch_bounds__(256, 2) void maxsim_kernel(
        const unsigned short* __restrict__ satN,
        const unsigned short* __restrict__ panoN,
        float* __restrict__ out) {
    __shared__ unsigned short Slds[2][128 * 64];   // 2 x 16 KB sat K-halves

    const int tid  = threadIdx.x;
    const int wid  = tid >> 6;
    const int lane = tid & 63;
    const int rl   = lane & 31;
    const int hi   = lane >> 5;

    const int bid = blockIdx.x;
    const int swz = (bid & 7) * 64 + (bid >> 3);   // XCD-contiguous (512 % 8 == 0)
    const int jg  = swz >> 5;                      // 0..15: sat j-group (8 tiles of 128)
    const int it  = swz & 31;                      // 0..31: pano panel (128 i-cols)

    const int wm = wid >> 1;                       // 0..1: j 64-half within tile
    const int wn = wid & 1;                        // 0..1: i 64-half (one a-image)

    // ---- B (pano) fragments: 64 i-cols x K=128, 64 VGPR, loaded once ----
    bf16x8 bfr[2][8];
    {
        const unsigned short* pb =
            panoN + ((size_t)(it * 128 + wn * 64 + rl)) * 128 + hi * 8;
        #pragma unroll
        for (int n = 0; n < 2; ++n)
            #pragma unroll
            for (int ks = 0; ks < 8; ++ks)
                bfr[n][ks] = *reinterpret_cast<const bf16x8*>(pb + (size_t)n * 32 * 128 + ks * 16);
    }

#define STAGE(t, kh) do {                                                      \
    const char* gb_ = (const char*)satN + ((size_t)(jg * 1024 + (t) * 128)) * 256 + (kh) * 128; \
    char* lb_ = (char*)&Slds[kh][0];                                           \
    _Pragma("unroll")                                                          \
    for (int i_ = 0; i_ < 4; ++i_) {                                           \
        int P_ = (wid * 4 + i_) * 1024 + lane * 16;                            \
        int r_ = P_ >> 7;                                                      \
        int g_ = ((P_ >> 4) & 7) ^ (r_ & 7);                                   \
        gload16(gb_ + (size_t)r_ * 256 + g_ * 16, lb_ + P_);                   \
    } } while (0)

#define COMPUTE(kh) do {                                                       \
    const char* sb_ = (const char*)&Slds[kh][0];                               \
    _Pragma("unroll")                                                          \
    for (int ks = 0; ks < 4; ++ks) {                                           \
        bf16x8 a_[2];                                                          \
        _Pragma("unroll")                                                      \
        for (int m = 0; m < 2; ++m) {                                          \
            int row = wm * 64 + m * 32 + rl;                                   \
            a_[m] = *(const bf16x8*)(sb_ + row * 128 + ((((ks << 1) | hi) ^ (row & 7)) << 4)); \
        }                                                                      \
        _Pragma("unroll")                                                      \
        for (int m = 0; m < 2; ++m)                                            \
            _Pragma("unroll")                                                  \
            for (int n = 0; n < 2; ++n)                                        \
                acc[m][n] = __builtin_amdgcn_mfma_f32_32x32x16_bf16(           \
                    a_[m], bfr[n][(kh) * 4 + ks], acc[m][n], 0, 0, 0);         \
    } } while (0)

    STAGE(0, 0);
    __syncthreads();

    #pragma unroll 1
    for (int t = 0; t < 8; ++t) {
        f32x16 acc[2][2] = {};

        STAGE(t, 1);                        // lands during COMPUTE(0)
        __builtin_amdgcn_sched_barrier(0);
        COMPUTE(0);
        __syncthreads();

        if (t < 7) {
            STAGE(t + 1, 0);                // lands during COMPUTE(1)
            __builtin_amdgcn_sched_barrier(0);
        }
        COMPUTE(1);
        __syncthreads();

        // epilogue: max_j within-lane (+hi-swap), sum_i butterfly over 32 col-lanes
        // C layout 32x32: row=(q&3)+8*(q>>2)+4*hi, col=lane&31
        float v0 = acc[0][0][0], v1 = acc[0][1][0];
        #pragma unroll
        for (int m = 0; m < 2; ++m)
            #pragma unroll
            for (int q = 0; q < 16; ++q) {
                if (m == 0 && q == 0) continue;
                v0 = fmaxf(v0, acc[m][0][q]);
                v1 = fmaxf(v1, acc[m][1][q]);
            }
        v0 = fmaxf(v0, __shfl_xor(v0, 32));
        v1 = fmaxf(v1, __shfl_xor(v1, 32));
        float s = v0 + v1;
        #pragma unroll
        for (int d = 1; d <= 16; d <<= 1) s += __shfl_xor(s, d);
        if (lane == 0) {
            int a = it * 2 + wn;
            int b = jg * 16 + t * 2 + wm;
            out[a * 256 + b] = s;
        }
    }
#undef STAGE
#undef COMPUTE
}

extern "C" void kernel_launch(void* const* d_in, const int* in_sizes, int n_in,
                              void* d_out, int out_size, void* d_ws, size_t ws_size,
                              hipStream_t stream) {
    const float* sat  = (const float*)d_in[0];   // [16384,128]
    const float* pano = (const float*)d_in[1];   // [ 4096,128]
    float* out = (float*)d_out;                  // [64,256]

    unsigned short* panoN = (unsigned short*)d_ws;        // 4096*128 bf16
    unsigned short* satN  = panoN + (size_t)4096 * 128;   // 16384*128 bf16

    normalize_all<<<2560, 256, 0, stream>>>(sat, pano, satN, panoN);
    maxsim_kernel<<<512, 256, 0, stream>>>(satN, panoN, out);
}